// Round 19
// baseline (185.715 us; speedup 1.0000x reference)
//
#include <hip/hip_runtime.h>

#define ABLK 512             // aggregation block (8 waves)
#define PBLK 512
#define PITER 16
#define EPB (PBLK * PITER)   // 8192 edges per partition block
#define F_INK 18
#define F_HIDK 16
#define CB 2048              // coarse bucket: nodes per bucket
#define CSH 11
#define MAXNC 512            // >= ceil(1e6/2048)=489
#define CAPB 10240           // padded per-bucket edge capacity (mean 8192 + 22 sigma)
#define SCAP CAPB            // sortB LDS stage (40 KB)
#define PSTG (PBLK * F_INK)  // k_pre stage: 9216 u32 = 36 KB (>= EPB and >= xf floats)

__device__ __forceinline__ unsigned f2bf(float f) {  // RNE f32->bf16 (finite inputs)
  unsigned u = __float_as_uint(f);
  return (u + 0x7fffu + ((u >> 16) & 1u)) >> 16;
}
__device__ __forceinline__ float bflo(unsigned u) { return __uint_as_float(u << 16); }
__device__ __forceinline__ float bfhi(unsigned u) { return __uint_as_float(u & 0xffff0000u); }

// ---------- k_pre: fill w/ LDS-staged local sort (blocks < nblk) || hw GEMV ----------
// epk rec = (dst & 2047) << 20 | src   (src < 2^20)
__global__ __launch_bounds__(PBLK) void k_pre(const int* __restrict__ rows,
                                              const int* __restrict__ cols,
                                              int* __restrict__ gcur,
                                              unsigned* __restrict__ epk,
                                              const float* __restrict__ x,
                                              const float* __restrict__ W1,
                                              uint4* __restrict__ hwb,
                                              int e, int n, int NC, int nblk) {
  __shared__ int hist[MAXNC];            // counts -> cursors
  __shared__ int lb[MAXNC];              // local exclusive bases
  __shared__ int gb[MAXNC];              // global reserved bases
  __shared__ unsigned stage[PSTG];       // 36 KB; fill uses 32 KB, GEMV aliases xf
  const int tid = threadIdx.x;
  if (blockIdx.x < nblk) {
    // ---- fill branch ----
    for (int j = tid; j < NC; j += PBLK) hist[j] = 0;
    __syncthreads();
    const int base = blockIdx.x * EPB;
    const int cnt = min(EPB, e - base);
    const int4* cols4 = (const int4*)(cols + base);
    const int4* rows4 = (const int4*)(rows + base);
    int4 c4[PITER / 4], r4[PITER / 4];
    // pass 1: registers + histogram
#pragma unroll
    for (int k = 0; k < PITER / 4; ++k) {
      int idx = k * PBLK + tid;
      int gi = base + idx * 4;
      if (gi + 3 < e) {
        c4[k] = cols4[idx];
        r4[k] = rows4[idx];
      } else {
        int cc[4], rr[4];
        for (int j = 0; j < 4; ++j) {
          int g = gi + j;
          if (g < e) { cc[j] = cols[g]; rr[j] = rows[g]; }
          else       { cc[j] = -1; rr[j] = 0; }
        }
        c4[k] = make_int4(cc[0], cc[1], cc[2], cc[3]);
        r4[k] = make_int4(rr[0], rr[1], rr[2], rr[3]);
      }
      int cc[4] = {c4[k].x, c4[k].y, c4[k].z, c4[k].w};
#pragma unroll
      for (int j = 0; j < 4; ++j)
        if (cc[j] >= 0) atomicAdd(&hist[cc[j] >> CSH], 1);
    }
    __syncthreads();
    // local exclusive scan over NC counters (1/thread) + global reservation
    int v = (tid < NC) ? hist[tid] : 0;
    lb[tid] = v;
    __syncthreads();
    for (int off = 1; off < MAXNC; off <<= 1) {
      int tv = (tid >= off) ? lb[tid - off] : 0;
      __syncthreads();
      lb[tid] += tv;
      __syncthreads();
    }
    lb[tid] -= v;              // exclusive prefix
    if (tid < NC) {
      gb[tid] = (v > 0) ? atomicAdd(&gcur[tid], v) + tid * CAPB : 0;
      hist[tid] = lb[tid];     // becomes local cursor
    }
    __syncthreads();
    // pass 2: scatter into LDS stage (bucket-major local order)
#pragma unroll
    for (int k = 0; k < PITER / 4; ++k) {
      int cc[4] = {c4[k].x, c4[k].y, c4[k].z, c4[k].w};
      int rr[4] = {r4[k].x, r4[k].y, r4[k].z, r4[k].w};
#pragma unroll
      for (int j = 0; j < 4; ++j) {
        if (cc[j] >= 0) {
          int bb = cc[j] >> CSH;
          int p = atomicAdd(&hist[bb], 1);
          stage[p] = ((unsigned)(cc[j] & (CB - 1)) << 20) | (unsigned)rr[j];
        }
      }
    }
    __syncthreads();
    // burst writeback: consecutive j -> consecutive dest within each bucket run
    for (int j = tid; j < cnt; j += PBLK) {
      int lo = 0, hi = NC - 1;
      while (lo < hi) {                      // largest b with lb[b] <= j
        int mid = (lo + hi + 1) >> 1;
        if (lb[mid] <= j) lo = mid; else hi = mid - 1;
      }
      int dest = gb[lo] + (j - lb[lo]);
      if (dest < (lo + 1) * CAPB) epk[dest] = stage[j];
    }
  } else {
    // ---- hw branch: hw = bf16(x @ W1), un-scaled; 2048 nodes per block ----
    float* xf = (float*)stage;   // 36 KB
    const int hb = blockIdx.x - nblk;
#pragma unroll
    for (int g = 0; g < CB / PBLK; ++g) {
      const int gbase = hb * CB + g * PBLK;
      if (gbase >= n) break;
      const int nrow = min(PBLK, n - gbase);
      const int lim = nrow * F_INK;
      __syncthreads();
      for (int t = tid; t < lim; t += PBLK)
        xf[t] = x[(size_t)gbase * F_INK + t];
      __syncthreads();
      if (tid < nrow) {
        int node = gbase + tid;
        float hw[F_HIDK];
#pragma unroll
        for (int f = 0; f < F_HIDK; ++f) hw[f] = 0.0f;
        const float* xi = &xf[tid * F_INK];
#pragma unroll
        for (int k = 0; k < F_INK; ++k) {
          float xk = xi[k];
#pragma unroll
          for (int f = 0; f < F_HIDK; ++f) hw[f] = fmaf(xk, W1[k * F_HIDK + f], hw[f]);
        }
        unsigned w[8];
#pragma unroll
        for (int p = 0; p < 8; ++p)
          w[p] = f2bf(hw[2 * p]) | (f2bf(hw[2 * p + 1]) << 16);
        hwb[(size_t)node * 2 + 0] = make_uint4(w[0], w[1], w[2], w[3]);
        hwb[(size_t)node * 2 + 1] = make_uint4(w[4], w[5], w[6], w[7]);
      }
    }
  }
}

// ---------- sortB: per bucket -> exact-dst order, noderng, dis, s1b = hw*dis ----------
__global__ __launch_bounds__(PBLK) void k_sortB(const unsigned* __restrict__ epk,
                                                const int* __restrict__ gcnt,
                                                const uint4* __restrict__ hwb,
                                                unsigned* __restrict__ sorted2,
                                                int2* __restrict__ noderng,
                                                float* __restrict__ dis,
                                                uint4* __restrict__ s1b, int n) {
  __shared__ int hist[CB];        // 8 KB
  __shared__ int psum[PBLK];      // 2 KB
  __shared__ unsigned stage[SCAP];// 40 KB
  const int b = blockIdx.x;
  const int s = b * CAPB;
  const int cnt = min(gcnt[b], CAPB);
  for (int j = threadIdx.x; j < CB; j += PBLK) hist[j] = 0;
  __syncthreads();
  // histogram (uint4-vectorized reads)
  const int cnt4 = cnt >> 2;
  const uint4* epk4 = (const uint4*)(epk + s);
  for (int i = threadIdx.x; i < cnt4; i += PBLK) {
    uint4 v = epk4[i];
    atomicAdd(&hist[v.x >> 20], 1);
    atomicAdd(&hist[v.y >> 20], 1);
    atomicAdd(&hist[v.z >> 20], 1);
    atomicAdd(&hist[v.w >> 20], 1);
  }
  for (int i = cnt4 * 4 + threadIdx.x; i < cnt; i += PBLK)
    atomicAdd(&hist[epk[s + i] >> 20], 1);
  __syncthreads();
  // exclusive scan over 2048 counters; thread owns 4 consecutive
  int loc[4];
  int sum = 0;
#pragma unroll
  for (int k = 0; k < 4; ++k) {
    int c = hist[threadIdx.x * 4 + k];
    loc[k] = sum;
    sum += c;
  }
  psum[threadIdx.x] = sum;
  __syncthreads();
  for (int off = 1; off < PBLK; off <<= 1) {
    int tv = (threadIdx.x >= off) ? psum[threadIdx.x - off] : 0;
    __syncthreads();
    psum[threadIdx.x] += tv;
    __syncthreads();
  }
  const int base0 = psum[threadIdx.x] - sum;
#pragma unroll
  for (int k = 0; k < 4; ++k) {
    int j = threadIdx.x * 4 + k;
    int bj = base0 + loc[k];
    int cj = ((k < 3) ? loc[k + 1] : sum) - loc[k];
    int node = (b << CSH) + j;
    if (node < n) {
      noderng[node] = make_int2(s + bj, s + bj + cj);
      dis[node] = rsqrtf((float)(cj + 1));
    }
    hist[j] = bj;  // becomes local cursor
  }
  __syncthreads();
  // permute in LDS, stream out sequentially (uint4 writeback)
  for (int i = threadIdx.x; i < cnt; i += PBLK) {
    unsigned rec = epk[s + i];
    int p = atomicAdd(&hist[rec >> 20], 1);
    stage[p] = rec & 0xFFFFFu;
  }
  __syncthreads();
  uint4* so4 = (uint4*)(sorted2 + s);
  const uint4* st4 = (const uint4*)stage;
  for (int j = threadIdx.x; j < cnt4; j += PBLK) so4[j] = st4[j];
  for (int j = cnt4 * 4 + threadIdx.x; j < cnt; j += PBLK) sorted2[s + j] = stage[j];
  // scale: s1b = bf16(hw * dis) for this bucket's nodes
#pragma unroll
  for (int g = 0; g < CB / PBLK; ++g) {
    int node = (b << CSH) + g * PBLK + (int)threadIdx.x;
    if (node < n) {
      float di = dis[node];
      uint4 a0 = hwb[(size_t)node * 2 + 0];
      uint4 a1 = hwb[(size_t)node * 2 + 1];
      unsigned w0 = f2bf(bflo(a0.x) * di) | (f2bf(bfhi(a0.x) * di) << 16);
      unsigned w1 = f2bf(bflo(a0.y) * di) | (f2bf(bfhi(a0.y) * di) << 16);
      unsigned w2 = f2bf(bflo(a0.z) * di) | (f2bf(bfhi(a0.z) * di) << 16);
      unsigned w3 = f2bf(bflo(a0.w) * di) | (f2bf(bfhi(a0.w) * di) << 16);
      unsigned w4 = f2bf(bflo(a1.x) * di) | (f2bf(bfhi(a1.x) * di) << 16);
      unsigned w5 = f2bf(bflo(a1.y) * di) | (f2bf(bfhi(a1.y) * di) << 16);
      unsigned w6 = f2bf(bflo(a1.z) * di) | (f2bf(bfhi(a1.z) * di) << 16);
      unsigned w7 = f2bf(bflo(a1.w) * di) | (f2bf(bfhi(a1.w) * di) << 16);
      s1b[(size_t)node * 2 + 0] = make_uint4(w0, w1, w2, w3);
      s1b[(size_t)node * 2 + 1] = make_uint4(w4, w5, w6, w7);
    }
  }
}

#define ACC8(V)                                         \
  acc[0] += bflo(V.x); acc[1] += bfhi(V.x);             \
  acc[2] += bflo(V.y); acc[3] += bfhi(V.y);             \
  acc[4] += bflo(V.z); acc[5] += bfhi(V.z);             \
  acc[6] += bflo(V.w); acc[7] += bfhi(V.w);

// ---------- layer 1: CSR run-walk, register accumulate, 2-deep prefetch + node2 ----------
__global__ __launch_bounds__(ABLK) void k_agg1(const unsigned* __restrict__ sorted2,
                                               const int2* __restrict__ noderng,
                                               const uint4* __restrict__ s1b,
                                               const float* __restrict__ dis,
                                               const float* __restrict__ b1,
                                               const float* __restrict__ W2,
                                               unsigned* __restrict__ s2b, int n) {
  const int q = threadIdx.x & 1;                       // 16B half of the 32B row
  const int node = blockIdx.x * (ABLK >> 1) + (threadIdx.x >> 1);
  if (node >= n) return;
  float di = dis[node];
  uint4 sv = s1b[(size_t)node * 2 + q];                // self term
  float acc[8] = {bflo(sv.x), bfhi(sv.x), bflo(sv.y), bfhi(sv.y),
                  bflo(sv.z), bfhi(sv.z), bflo(sv.w), bfhi(sv.w)};
  int2 rng = noderng[node];
  int i = rng.x;
  const int re = rng.y;
  const int len = re - i;
  if (len > 0) {
    uint4 v0 = s1b[(size_t)sorted2[i] * 2 + q];
    if (len > 1) {
      uint4 v1 = s1b[(size_t)sorted2[i + 1] * 2 + q];
      i += 2;
      while (i < re) {
        uint4 v2 = s1b[(size_t)sorted2[i] * 2 + q];    // 2-deep prefetch
        ACC8(v0);
        v0 = v1; v1 = v2;
        ++i;
      }
      ACC8(v0);
      v0 = v1;
    }
    ACC8(v0);
  }
  // node2 epilogue: lane owns feats f = q*8+k; h = relu(di*acc+b1); o = h@W2
  float p0 = 0.f, p1 = 0.f;
#pragma unroll
  for (int k = 0; k < 8; ++k) {
    int f = q * 8 + k;
    float h = fmaxf(fmaf(di, acc[k], b1[f]), 0.0f);
    p0 = fmaf(h, W2[f * 2 + 0], p0);
    p1 = fmaf(h, W2[f * 2 + 1], p1);
  }
  p0 += __shfl_xor(p0, 1);
  p1 += __shfl_xor(p1, 1);
  if (q == 0)
    s2b[node] = f2bf(p0 * di) | (f2bf(p1 * di) << 16);
}

// ---------- layer 2: CSR run-walk over bf16 s2 (L2-resident) + log_softmax ----------
__global__ __launch_bounds__(ABLK) void k_agg2(const unsigned* __restrict__ sorted2,
                                               const int2* __restrict__ noderng,
                                               const unsigned* __restrict__ s2b,
                                               const float* __restrict__ dis,
                                               const float* __restrict__ b2,
                                               float* __restrict__ out, int n) {
  const int node = blockIdx.x * ABLK + threadIdx.x;
  if (node >= n) return;
  float di = dis[node];
  unsigned sv = s2b[node];
  float a0 = bflo(sv), a1 = bfhi(sv);
  int2 rng = noderng[node];
  int i = rng.x;
  const int re = rng.y;
  const int len = re - i;
  if (len > 0) {
    unsigned v0 = s2b[sorted2[i]];
    if (len > 1) {
      unsigned v1 = s2b[sorted2[i + 1]];
      i += 2;
      while (i < re) {
        unsigned v2 = s2b[sorted2[i]];
        a0 += bflo(v0); a1 += bfhi(v0);
        v0 = v1; v1 = v2;
        ++i;
      }
      a0 += bflo(v0); a1 += bfhi(v0);
      v0 = v1;
    }
    a0 += bflo(v0); a1 += bfhi(v0);
  }
  float o0 = fmaf(di, a0, b2[0]);
  float o1 = fmaf(di, a1, b2[1]);
  float m = fmaxf(o0, o1);
  float lse = m + logf(expf(o0 - m) + expf(o1 - m));
  float2 r;
  r.x = o0 - lse;
  r.y = o1 - lse;
  ((float2*)out)[node] = r;
}

extern "C" void kernel_launch(void* const* d_in, const int* in_sizes, int n_in,
                              void* d_out, int out_size, void* d_ws, size_t ws_size,
                              hipStream_t stream) {
  const float* x  = (const float*)d_in[0];
  const float* W1 = (const float*)d_in[1];
  const float* b1 = (const float*)d_in[2];
  const float* W2 = (const float*)d_in[3];
  const float* b2 = (const float*)d_in[4];
  const int*   ei = (const int*)d_in[5];
  const int n = in_sizes[0] / F_INK;
  const int e = in_sizes[5] / 2;
  const int* rows = ei;      // edge_index[0] = source
  const int* cols = ei + e;  // edge_index[1] = target

  const int NC = (n + CB - 1) / CB;      // 489 coarse buckets
  const int nblk = (e + EPB - 1) / EPB;  // 489 partition blocks

  char* ws = (char*)d_ws;
  size_t off = 0;
  auto alloc = [&](size_t bytes) {
    void* p = ws + off;
    off = (off + bytes + 15) & ~(size_t)15;
    return p;
  };
  float* dis        = (float*)alloc((size_t)n * 4);
  uint4* hwb        = (uint4*)alloc((size_t)n * 32);          // bf16 hw (un-scaled)
  uint4* s1b        = (uint4*)alloc((size_t)n * 32);          // bf16 s1 = hw*dis
  unsigned* s2b     = (unsigned*)alloc((size_t)n * 4);        // bf16 s2, 4 B/node
  unsigned* epk     = (unsigned*)alloc((size_t)NC * CAPB * 4);    // padded, ~20 MB
  unsigned* sorted2 = (unsigned*)alloc((size_t)NC * CAPB * 4);    // padded, ~20 MB
  int2* noderng     = (int2*)alloc((size_t)n * 8);
  int* gcur         = (int*)alloc((size_t)NC * 4);
  float* outp = (float*)d_out;

  (void)hipMemsetAsync(gcur, 0, (size_t)NC * 4, stream);
  k_pre  <<<nblk + NC, PBLK, 0, stream>>>(rows, cols, gcur, epk, x, W1, hwb,
                                          e, n, NC, nblk);
  k_sortB<<<NC, PBLK, 0, stream>>>(epk, gcur, hwb, sorted2, noderng, dis, s1b, n);
  k_agg1 <<<(n + (ABLK / 2) - 1) / (ABLK / 2), ABLK, 0, stream>>>(sorted2, noderng, s1b,
                                                                  dis, b1, W2, s2b, n);
  k_agg2 <<<(n + ABLK - 1) / ABLK, ABLK, 0, stream>>>(sorted2, noderng, s2b, dis, b2,
                                                      outp, n);
}

// Round 20
// 180.598 us; speedup vs baseline: 1.0283x; 1.0283x over previous
//
#include <hip/hip_runtime.h>

#define ABLK 512             // aggregation block (8 waves)
#define PBLK 512
#define PITER 16
#define EPB (PBLK * PITER)   // 8192 edges per partition block
#define F_INK 18
#define F_HIDK 16
#define CB 2048              // coarse bucket: nodes per bucket
#define CSH 11
#define MAXNC 512            // >= ceil(1e6/2048)=489
#define CAPB 10240           // padded per-bucket edge capacity (mean 8192 + 22 sigma)
#define SCAP CAPB            // sortB LDS stage (40 KB)
#define PSTG (PBLK * F_INK)  // k_pre stage: 9216 u32 = 36 KB (>= EPB and >= xf floats)

__device__ __forceinline__ unsigned f2bf(float f) {  // RNE f32->bf16 (finite inputs)
  unsigned u = __float_as_uint(f);
  return (u + 0x7fffu + ((u >> 16) & 1u)) >> 16;
}
__device__ __forceinline__ float bflo(unsigned u) { return __uint_as_float(u << 16); }
__device__ __forceinline__ float bfhi(unsigned u) { return __uint_as_float(u & 0xffff0000u); }

// ---------- k_pre: fill w/ LDS-staged local sort (blocks < nblk) || hw GEMV ----------
// epk rec = (dst & 2047) << 20 | src   (src < 2^20)
__global__ __launch_bounds__(PBLK) void k_pre(const int* __restrict__ rows,
                                              const int* __restrict__ cols,
                                              int* __restrict__ gcur,
                                              unsigned* __restrict__ epk,
                                              const float* __restrict__ x,
                                              const float* __restrict__ W1,
                                              uint4* __restrict__ hwb,
                                              int e, int n, int NC, int nblk) {
  __shared__ int hist[MAXNC];            // counts -> cursors
  __shared__ int lb[MAXNC];              // local exclusive bases (lb[NC] == cnt)
  __shared__ int gb[MAXNC];              // global reserved bases
  __shared__ unsigned stage[PSTG];       // 36 KB; fill uses 32 KB, GEMV aliases xf
  const int tid = threadIdx.x;
  if (blockIdx.x < nblk) {
    // ---- fill branch ----
    for (int j = tid; j < NC; j += PBLK) hist[j] = 0;
    __syncthreads();
    const int base = blockIdx.x * EPB;
    const int cnt = min(EPB, e - base);
    const int4* cols4 = (const int4*)(cols + base);
    const int4* rows4 = (const int4*)(rows + base);
    int4 c4[PITER / 4], r4[PITER / 4];
    // pass 1: registers + histogram
#pragma unroll
    for (int k = 0; k < PITER / 4; ++k) {
      int idx = k * PBLK + tid;
      int gi = base + idx * 4;
      if (gi + 3 < e) {
        c4[k] = cols4[idx];
        r4[k] = rows4[idx];
      } else {
        int cc[4], rr[4];
        for (int j = 0; j < 4; ++j) {
          int g = gi + j;
          if (g < e) { cc[j] = cols[g]; rr[j] = rows[g]; }
          else       { cc[j] = -1; rr[j] = 0; }
        }
        c4[k] = make_int4(cc[0], cc[1], cc[2], cc[3]);
        r4[k] = make_int4(rr[0], rr[1], rr[2], rr[3]);
      }
      int cc[4] = {c4[k].x, c4[k].y, c4[k].z, c4[k].w};
#pragma unroll
      for (int j = 0; j < 4; ++j)
        if (cc[j] >= 0) atomicAdd(&hist[cc[j] >> CSH], 1);
    }
    __syncthreads();
    // local exclusive scan over NC counters (1/thread) + global reservation
    int v = (tid < NC) ? hist[tid] : 0;
    lb[tid] = v;
    __syncthreads();
    for (int off = 1; off < MAXNC; off <<= 1) {
      int tv = (tid >= off) ? lb[tid - off] : 0;
      __syncthreads();
      lb[tid] += tv;
      __syncthreads();
    }
    lb[tid] -= v;              // exclusive prefix; lb[j] for j>=NC equals total cnt
    if (tid < NC) {
      gb[tid] = (v > 0) ? atomicAdd(&gcur[tid], v) + tid * CAPB : tid * CAPB;
      hist[tid] = lb[tid];     // becomes local cursor
    }
    __syncthreads();
    // pass 2: scatter into LDS stage (bucket-major local order)
#pragma unroll
    for (int k = 0; k < PITER / 4; ++k) {
      int cc[4] = {c4[k].x, c4[k].y, c4[k].z, c4[k].w};
      int rr[4] = {r4[k].x, r4[k].y, r4[k].z, r4[k].w};
#pragma unroll
      for (int j = 0; j < 4; ++j) {
        if (cc[j] >= 0) {
          int bb = cc[j] >> CSH;
          int p = atomicAdd(&hist[bb], 1);
          stage[p] = ((unsigned)(cc[j] & (CB - 1)) << 20) | (unsigned)rr[j];
        }
      }
    }
    __syncthreads();
    // burst writeback: 16-lane group per bucket run (no search)
    const int g16 = tid >> 4;        // 0..31
    const int l16 = tid & 15;
    for (int b = g16; b < NC; b += 32) {
      int st = lb[b];
      int en = lb[b + 1];            // lb[NC] == cnt (scan of zeros beyond NC)
      int gbs = gb[b];
      int lim = min(en - st, (b + 1) * CAPB - gbs);   // overflow guard
      for (int j = l16; j < lim; j += 16)
        epk[gbs + j] = stage[st + j];
    }
  } else {
    // ---- hw branch: hw = bf16(x @ W1), un-scaled; 2048 nodes per block ----
    float* xf = (float*)stage;   // 36 KB
    const int hb = blockIdx.x - nblk;
#pragma unroll
    for (int g = 0; g < CB / PBLK; ++g) {
      const int gbase = hb * CB + g * PBLK;
      if (gbase >= n) break;
      const int nrow = min(PBLK, n - gbase);
      const int lim = nrow * F_INK;
      __syncthreads();
      if ((lim & 3) == 0) {
        const float4* x4 = (const float4*)(x + (size_t)gbase * F_INK);
        float4* xf4 = (float4*)xf;
        for (int t = tid; t < (lim >> 2); t += PBLK) xf4[t] = x4[t];
      } else {
        for (int t = tid; t < lim; t += PBLK)
          xf[t] = x[(size_t)gbase * F_INK + t];
      }
      __syncthreads();
      if (tid < nrow) {
        int node = gbase + tid;
        float hw[F_HIDK];
#pragma unroll
        for (int f = 0; f < F_HIDK; ++f) hw[f] = 0.0f;
        const float* xi = &xf[tid * F_INK];
#pragma unroll
        for (int k = 0; k < F_INK; ++k) {
          float xk = xi[k];
#pragma unroll
          for (int f = 0; f < F_HIDK; ++f) hw[f] = fmaf(xk, W1[k * F_HIDK + f], hw[f]);
        }
        unsigned w[8];
#pragma unroll
        for (int p = 0; p < 8; ++p)
          w[p] = f2bf(hw[2 * p]) | (f2bf(hw[2 * p + 1]) << 16);
        hwb[(size_t)node * 2 + 0] = make_uint4(w[0], w[1], w[2], w[3]);
        hwb[(size_t)node * 2 + 1] = make_uint4(w[4], w[5], w[6], w[7]);
      }
    }
  }
}

// ---------- sortB: per bucket -> exact-dst order, noderng, dis, s1b = hw*dis ----------
__global__ __launch_bounds__(PBLK) void k_sortB(const unsigned* __restrict__ epk,
                                                const int* __restrict__ gcnt,
                                                const uint4* __restrict__ hwb,
                                                unsigned* __restrict__ sorted2,
                                                int2* __restrict__ noderng,
                                                float* __restrict__ dis,
                                                uint4* __restrict__ s1b, int n) {
  __shared__ int hist[CB];        // 8 KB
  __shared__ int psum[PBLK];      // 2 KB
  __shared__ unsigned stage[SCAP];// 40 KB
  const int b = blockIdx.x;
  const int s = b * CAPB;
  const int cnt = min(gcnt[b], CAPB);
  for (int j = threadIdx.x; j < CB; j += PBLK) hist[j] = 0;
  __syncthreads();
  // histogram (uint4-vectorized reads)
  const int cnt4 = cnt >> 2;
  const uint4* epk4 = (const uint4*)(epk + s);
  for (int i = threadIdx.x; i < cnt4; i += PBLK) {
    uint4 v = epk4[i];
    atomicAdd(&hist[v.x >> 20], 1);
    atomicAdd(&hist[v.y >> 20], 1);
    atomicAdd(&hist[v.z >> 20], 1);
    atomicAdd(&hist[v.w >> 20], 1);
  }
  for (int i = cnt4 * 4 + threadIdx.x; i < cnt; i += PBLK)
    atomicAdd(&hist[epk[s + i] >> 20], 1);
  __syncthreads();
  // exclusive scan over 2048 counters; thread owns 4 consecutive
  int loc[4];
  int sum = 0;
#pragma unroll
  for (int k = 0; k < 4; ++k) {
    int c = hist[threadIdx.x * 4 + k];
    loc[k] = sum;
    sum += c;
  }
  psum[threadIdx.x] = sum;
  __syncthreads();
  for (int off = 1; off < PBLK; off <<= 1) {
    int tv = (threadIdx.x >= off) ? psum[threadIdx.x - off] : 0;
    __syncthreads();
    psum[threadIdx.x] += tv;
    __syncthreads();
  }
  const int base0 = psum[threadIdx.x] - sum;
#pragma unroll
  for (int k = 0; k < 4; ++k) {
    int j = threadIdx.x * 4 + k;
    int bj = base0 + loc[k];
    int cj = ((k < 3) ? loc[k + 1] : sum) - loc[k];
    int node = (b << CSH) + j;
    if (node < n) {
      noderng[node] = make_int2(s + bj, s + bj + cj);
      dis[node] = rsqrtf((float)(cj + 1));
    }
    hist[j] = bj;  // becomes local cursor
  }
  __syncthreads();
  // permute in LDS, stream out sequentially (uint4 writeback)
  for (int i = threadIdx.x; i < cnt; i += PBLK) {
    unsigned rec = epk[s + i];
    int p = atomicAdd(&hist[rec >> 20], 1);
    stage[p] = rec & 0xFFFFFu;
  }
  __syncthreads();
  uint4* so4 = (uint4*)(sorted2 + s);
  const uint4* st4 = (const uint4*)stage;
  for (int j = threadIdx.x; j < cnt4; j += PBLK) so4[j] = st4[j];
  for (int j = cnt4 * 4 + threadIdx.x; j < cnt; j += PBLK) sorted2[s + j] = stage[j];
  // scale: s1b = bf16(hw * dis) for this bucket's nodes
#pragma unroll
  for (int g = 0; g < CB / PBLK; ++g) {
    int node = (b << CSH) + g * PBLK + (int)threadIdx.x;
    if (node < n) {
      float di = dis[node];
      uint4 a0 = hwb[(size_t)node * 2 + 0];
      uint4 a1 = hwb[(size_t)node * 2 + 1];
      unsigned w0 = f2bf(bflo(a0.x) * di) | (f2bf(bfhi(a0.x) * di) << 16);
      unsigned w1 = f2bf(bflo(a0.y) * di) | (f2bf(bfhi(a0.y) * di) << 16);
      unsigned w2 = f2bf(bflo(a0.z) * di) | (f2bf(bfhi(a0.z) * di) << 16);
      unsigned w3 = f2bf(bflo(a0.w) * di) | (f2bf(bfhi(a0.w) * di) << 16);
      unsigned w4 = f2bf(bflo(a1.x) * di) | (f2bf(bfhi(a1.x) * di) << 16);
      unsigned w5 = f2bf(bflo(a1.y) * di) | (f2bf(bfhi(a1.y) * di) << 16);
      unsigned w6 = f2bf(bflo(a1.z) * di) | (f2bf(bfhi(a1.z) * di) << 16);
      unsigned w7 = f2bf(bflo(a1.w) * di) | (f2bf(bfhi(a1.w) * di) << 16);
      s1b[(size_t)node * 2 + 0] = make_uint4(w0, w1, w2, w3);
      s1b[(size_t)node * 2 + 1] = make_uint4(w4, w5, w6, w7);
    }
  }
}

#define ACC8(V)                                         \
  acc[0] += bflo(V.x); acc[1] += bfhi(V.x);             \
  acc[2] += bflo(V.y); acc[3] += bfhi(V.y);             \
  acc[4] += bflo(V.z); acc[5] += bfhi(V.z);             \
  acc[6] += bflo(V.w); acc[7] += bfhi(V.w);

// ---------- layer 1: CSR run-walk, register accumulate, 2-deep prefetch + node2 ----------
__global__ __launch_bounds__(ABLK) void k_agg1(const unsigned* __restrict__ sorted2,
                                               const int2* __restrict__ noderng,
                                               const uint4* __restrict__ s1b,
                                               const float* __restrict__ dis,
                                               const float* __restrict__ b1,
                                               const float* __restrict__ W2,
                                               unsigned* __restrict__ s2b, int n) {
  const int q = threadIdx.x & 1;                       // 16B half of the 32B row
  const int node = blockIdx.x * (ABLK >> 1) + (threadIdx.x >> 1);
  if (node >= n) return;
  float di = dis[node];
  uint4 sv = s1b[(size_t)node * 2 + q];                // self term
  float acc[8] = {bflo(sv.x), bfhi(sv.x), bflo(sv.y), bfhi(sv.y),
                  bflo(sv.z), bfhi(sv.z), bflo(sv.w), bfhi(sv.w)};
  int2 rng = noderng[node];
  int i = rng.x;
  const int re = rng.y;
  const int len = re - i;
  if (len > 0) {
    uint4 v0 = s1b[(size_t)sorted2[i] * 2 + q];
    if (len > 1) {
      uint4 v1 = s1b[(size_t)sorted2[i + 1] * 2 + q];
      i += 2;
      while (i < re) {
        uint4 v2 = s1b[(size_t)sorted2[i] * 2 + q];    // 2-deep prefetch
        ACC8(v0);
        v0 = v1; v1 = v2;
        ++i;
      }
      ACC8(v0);
      v0 = v1;
    }
    ACC8(v0);
  }
  // node2 epilogue: lane owns feats f = q*8+k; h = relu(di*acc+b1); o = h@W2
  float p0 = 0.f, p1 = 0.f;
#pragma unroll
  for (int k = 0; k < 8; ++k) {
    int f = q * 8 + k;
    float h = fmaxf(fmaf(di, acc[k], b1[f]), 0.0f);
    p0 = fmaf(h, W2[f * 2 + 0], p0);
    p1 = fmaf(h, W2[f * 2 + 1], p1);
  }
  p0 += __shfl_xor(p0, 1);
  p1 += __shfl_xor(p1, 1);
  if (q == 0)
    s2b[node] = f2bf(p0 * di) | (f2bf(p1 * di) << 16);
}

// ---------- layer 2: CSR run-walk over bf16 s2 (L2-resident) + log_softmax ----------
__global__ __launch_bounds__(ABLK) void k_agg2(const unsigned* __restrict__ sorted2,
                                               const int2* __restrict__ noderng,
                                               const unsigned* __restrict__ s2b,
                                               const float* __restrict__ dis,
                                               const float* __restrict__ b2,
                                               float* __restrict__ out, int n) {
  const int node = blockIdx.x * ABLK + threadIdx.x;
  if (node >= n) return;
  float di = dis[node];
  unsigned sv = s2b[node];
  float a0 = bflo(sv), a1 = bfhi(sv);
  int2 rng = noderng[node];
  int i = rng.x;
  const int re = rng.y;
  const int len = re - i;
  if (len > 0) {
    unsigned v0 = s2b[sorted2[i]];
    if (len > 1) {
      unsigned v1 = s2b[sorted2[i + 1]];
      i += 2;
      while (i < re) {
        unsigned v2 = s2b[sorted2[i]];
        a0 += bflo(v0); a1 += bfhi(v0);
        v0 = v1; v1 = v2;
        ++i;
      }
      a0 += bflo(v0); a1 += bfhi(v0);
      v0 = v1;
    }
    a0 += bflo(v0); a1 += bfhi(v0);
  }
  float o0 = fmaf(di, a0, b2[0]);
  float o1 = fmaf(di, a1, b2[1]);
  float m = fmaxf(o0, o1);
  float lse = m + logf(expf(o0 - m) + expf(o1 - m));
  float2 r;
  r.x = o0 - lse;
  r.y = o1 - lse;
  ((float2*)out)[node] = r;
}

extern "C" void kernel_launch(void* const* d_in, const int* in_sizes, int n_in,
                              void* d_out, int out_size, void* d_ws, size_t ws_size,
                              hipStream_t stream) {
  const float* x  = (const float*)d_in[0];
  const float* W1 = (const float*)d_in[1];
  const float* b1 = (const float*)d_in[2];
  const float* W2 = (const float*)d_in[3];
  const float* b2 = (const float*)d_in[4];
  const int*   ei = (const int*)d_in[5];
  const int n = in_sizes[0] / F_INK;
  const int e = in_sizes[5] / 2;
  const int* rows = ei;      // edge_index[0] = source
  const int* cols = ei + e;  // edge_index[1] = target

  const int NC = (n + CB - 1) / CB;      // 489 coarse buckets
  const int nblk = (e + EPB - 1) / EPB;  // 489 partition blocks

  char* ws = (char*)d_ws;
  size_t off = 0;
  auto alloc = [&](size_t bytes) {
    void* p = ws + off;
    off = (off + bytes + 15) & ~(size_t)15;
    return p;
  };
  float* dis        = (float*)alloc((size_t)n * 4);
  uint4* hwb        = (uint4*)alloc((size_t)n * 32);          // bf16 hw (un-scaled)
  uint4* s1b        = (uint4*)alloc((size_t)n * 32);          // bf16 s1 = hw*dis
  unsigned* s2b     = (unsigned*)alloc((size_t)n * 4);        // bf16 s2, 4 B/node
  unsigned* epk     = (unsigned*)alloc((size_t)NC * CAPB * 4);    // padded, ~20 MB
  unsigned* sorted2 = (unsigned*)alloc((size_t)NC * CAPB * 4);    // padded, ~20 MB
  int2* noderng     = (int2*)alloc((size_t)n * 8);
  int* gcur         = (int*)alloc((size_t)NC * 4);
  float* outp = (float*)d_out;

  (void)hipMemsetAsync(gcur, 0, (size_t)NC * 4, stream);
  k_pre  <<<nblk + NC, PBLK, 0, stream>>>(rows, cols, gcur, epk, x, W1, hwb,
                                          e, n, NC, nblk);
  k_sortB<<<NC, PBLK, 0, stream>>>(epk, gcur, hwb, sorted2, noderng, dis, s1b, n);
  k_agg1 <<<(n + (ABLK / 2) - 1) / (ABLK / 2), ABLK, 0, stream>>>(sorted2, noderng, s1b,
                                                                  dis, b1, W2, s2b, n);
  k_agg2 <<<(n + ABLK - 1) / ABLK, ABLK, 0, stream>>>(sorted2, noderng, s2b, dis, b2,
                                                      outp, n);
}

// Round 21
// 177.263 us; speedup vs baseline: 1.0477x; 1.0188x over previous
//
#include <hip/hip_runtime.h>

#define ABLK 512             // aggregation block (8 waves)
#define PBLK 512
#define PITER 32
#define EPB (PBLK * PITER)   // 16384 edges per partition block
#define F_INK 18
#define F_HIDK 16
#define CB 2048              // coarse bucket: nodes per bucket
#define CSH 11
#define MAXNC 512            // >= ceil(1e6/2048)=489
#define CAPB 10240           // padded per-bucket edge capacity (mean 8192 + 22 sigma)
#define SCAP CAPB            // sortB LDS stage (40 KB)

__device__ __forceinline__ unsigned f2bf(float f) {  // RNE f32->bf16 (finite inputs)
  unsigned u = __float_as_uint(f);
  return (u + 0x7fffu + ((u >> 16) & 1u)) >> 16;
}
__device__ __forceinline__ float bflo(unsigned u) { return __uint_as_float(u << 16); }
__device__ __forceinline__ float bfhi(unsigned u) { return __uint_as_float(u & 0xffff0000u); }

// ---------- k_pre: fill w/ dyn-LDS staged local sort (blocks < nblk) || hw GEMV ----------
// epk rec = (dst & 2047) << 20 | src   (src < 2^20)
// dynamic LDS: EPB u32 = 64 KB (fill stage; GEMV aliases 36 KB as xf)
__global__ __launch_bounds__(PBLK) void k_pre(const int* __restrict__ rows,
                                              const int* __restrict__ cols,
                                              int* __restrict__ gcur,
                                              unsigned* __restrict__ epk,
                                              const float* __restrict__ x,
                                              const float* __restrict__ W1,
                                              uint4* __restrict__ hwb,
                                              int e, int n, int NC, int nblk) {
  __shared__ int hist[MAXNC];            // counts -> cursors
  __shared__ int lb[MAXNC];              // local exclusive bases (lb[NC..511] == cnt)
  __shared__ int gb[MAXNC];              // global reserved bases
  extern __shared__ unsigned stage[];    // 64 KB dynamic
  const int tid = threadIdx.x;
  if (blockIdx.x < nblk) {
    // ---- fill branch ----
    for (int j = tid; j < NC; j += PBLK) hist[j] = 0;
    __syncthreads();
    const int base = blockIdx.x * EPB;
    const int cnt = min(EPB, e - base);
    const int4* cols4 = (const int4*)(cols + base);
    const int4* rows4 = (const int4*)(rows + base);
    int4 c4[PITER / 4], r4[PITER / 4];
    // pass 1: registers + histogram
#pragma unroll
    for (int k = 0; k < PITER / 4; ++k) {
      int idx = k * PBLK + tid;
      int gi = base + idx * 4;
      if (gi + 3 < e) {
        c4[k] = cols4[idx];
        r4[k] = rows4[idx];
      } else {
        int cc[4], rr[4];
        for (int j = 0; j < 4; ++j) {
          int g = gi + j;
          if (g < e) { cc[j] = cols[g]; rr[j] = rows[g]; }
          else       { cc[j] = -1; rr[j] = 0; }
        }
        c4[k] = make_int4(cc[0], cc[1], cc[2], cc[3]);
        r4[k] = make_int4(rr[0], rr[1], rr[2], rr[3]);
      }
      int cc[4] = {c4[k].x, c4[k].y, c4[k].z, c4[k].w};
#pragma unroll
      for (int j = 0; j < 4; ++j)
        if (cc[j] >= 0) atomicAdd(&hist[cc[j] >> CSH], 1);
    }
    __syncthreads();
    // local exclusive scan over NC counters (1/thread) + global reservation
    int v = (tid < NC) ? hist[tid] : 0;
    lb[tid] = v;
    __syncthreads();
    for (int off = 1; off < MAXNC; off <<= 1) {
      int tv = (tid >= off) ? lb[tid - off] : 0;
      __syncthreads();
      lb[tid] += tv;
      __syncthreads();
    }
    lb[tid] -= v;              // exclusive prefix; lb[j>=NC] == cnt
    if (tid < NC) {
      gb[tid] = (v > 0) ? atomicAdd(&gcur[tid], v) + tid * CAPB : tid * CAPB;
      hist[tid] = lb[tid];     // becomes local cursor
    }
    __syncthreads();
    // pass 2: scatter into LDS stage (bucket-major local order)
#pragma unroll
    for (int k = 0; k < PITER / 4; ++k) {
      int cc[4] = {c4[k].x, c4[k].y, c4[k].z, c4[k].w};
      int rr[4] = {r4[k].x, r4[k].y, r4[k].z, r4[k].w};
#pragma unroll
      for (int j = 0; j < 4; ++j) {
        if (cc[j] >= 0) {
          int bb = cc[j] >> CSH;
          int p = atomicAdd(&hist[bb], 1);
          stage[p] = ((unsigned)(cc[j] & (CB - 1)) << 20) | (unsigned)rr[j];
        }
      }
    }
    __syncthreads();
    // burst writeback: 16-lane group per bucket run (runs avg ~34 edges)
    const int g16 = tid >> 4;        // 0..31
    const int l16 = tid & 15;
    for (int b = g16; b < NC; b += 32) {
      int st = lb[b];
      int en = lb[b + 1];
      int gbs = gb[b];
      int lim = min(en - st, (b + 1) * CAPB - gbs);   // overflow guard
      for (int j = l16; j < lim; j += 16)
        epk[gbs + j] = stage[st + j];
    }
  } else {
    // ---- hw branch: hw = bf16(x @ W1), un-scaled; 2048 nodes per block ----
    float* xf = (float*)stage;   // uses 36 KB of the dynamic buffer
    const int hb = blockIdx.x - nblk;
#pragma unroll
    for (int g = 0; g < CB / PBLK; ++g) {
      const int gbase = hb * CB + g * PBLK;
      if (gbase >= n) break;
      const int nrow = min(PBLK, n - gbase);
      const int lim = nrow * F_INK;
      __syncthreads();
      if ((lim & 3) == 0) {
        const float4* x4 = (const float4*)(x + (size_t)gbase * F_INK);
        float4* xf4 = (float4*)xf;
        for (int t = tid; t < (lim >> 2); t += PBLK) xf4[t] = x4[t];
      } else {
        for (int t = tid; t < lim; t += PBLK)
          xf[t] = x[(size_t)gbase * F_INK + t];
      }
      __syncthreads();
      if (tid < nrow) {
        int node = gbase + tid;
        float hw[F_HIDK];
#pragma unroll
        for (int f = 0; f < F_HIDK; ++f) hw[f] = 0.0f;
        const float* xi = &xf[tid * F_INK];
#pragma unroll
        for (int k = 0; k < F_INK; ++k) {
          float xk = xi[k];
#pragma unroll
          for (int f = 0; f < F_HIDK; ++f) hw[f] = fmaf(xk, W1[k * F_HIDK + f], hw[f]);
        }
        unsigned w[8];
#pragma unroll
        for (int p = 0; p < 8; ++p)
          w[p] = f2bf(hw[2 * p]) | (f2bf(hw[2 * p + 1]) << 16);
        hwb[(size_t)node * 2 + 0] = make_uint4(w[0], w[1], w[2], w[3]);
        hwb[(size_t)node * 2 + 1] = make_uint4(w[4], w[5], w[6], w[7]);
      }
    }
  }
}

// ---------- sortB: per bucket -> exact-dst order, noderng, dis, s1b = hw*dis ----------
__global__ __launch_bounds__(PBLK) void k_sortB(const unsigned* __restrict__ epk,
                                                const int* __restrict__ gcnt,
                                                const uint4* __restrict__ hwb,
                                                unsigned* __restrict__ sorted2,
                                                int2* __restrict__ noderng,
                                                float* __restrict__ dis,
                                                uint4* __restrict__ s1b, int n) {
  __shared__ int hist[CB];        // 8 KB
  __shared__ int psum[PBLK];      // 2 KB
  __shared__ unsigned stage[SCAP];// 40 KB
  const int b = blockIdx.x;
  const int s = b * CAPB;
  const int cnt = min(gcnt[b], CAPB);
  for (int j = threadIdx.x; j < CB; j += PBLK) hist[j] = 0;
  __syncthreads();
  // histogram (uint4-vectorized reads)
  const int cnt4 = cnt >> 2;
  const uint4* epk4 = (const uint4*)(epk + s);
  for (int i = threadIdx.x; i < cnt4; i += PBLK) {
    uint4 v = epk4[i];
    atomicAdd(&hist[v.x >> 20], 1);
    atomicAdd(&hist[v.y >> 20], 1);
    atomicAdd(&hist[v.z >> 20], 1);
    atomicAdd(&hist[v.w >> 20], 1);
  }
  for (int i = cnt4 * 4 + threadIdx.x; i < cnt; i += PBLK)
    atomicAdd(&hist[epk[s + i] >> 20], 1);
  __syncthreads();
  // exclusive scan over 2048 counters; thread owns 4 consecutive
  int loc[4];
  int sum = 0;
#pragma unroll
  for (int k = 0; k < 4; ++k) {
    int c = hist[threadIdx.x * 4 + k];
    loc[k] = sum;
    sum += c;
  }
  psum[threadIdx.x] = sum;
  __syncthreads();
  for (int off = 1; off < PBLK; off <<= 1) {
    int tv = (threadIdx.x >= off) ? psum[threadIdx.x - off] : 0;
    __syncthreads();
    psum[threadIdx.x] += tv;
    __syncthreads();
  }
  const int base0 = psum[threadIdx.x] - sum;
#pragma unroll
  for (int k = 0; k < 4; ++k) {
    int j = threadIdx.x * 4 + k;
    int bj = base0 + loc[k];
    int cj = ((k < 3) ? loc[k + 1] : sum) - loc[k];
    int node = (b << CSH) + j;
    if (node < n) {
      noderng[node] = make_int2(s + bj, s + bj + cj);
      dis[node] = rsqrtf((float)(cj + 1));
    }
    hist[j] = bj;  // becomes local cursor
  }
  __syncthreads();
  // permute in LDS, stream out sequentially (uint4 writeback)
  for (int i = threadIdx.x; i < cnt; i += PBLK) {
    unsigned rec = epk[s + i];
    int p = atomicAdd(&hist[rec >> 20], 1);
    stage[p] = rec & 0xFFFFFu;
  }
  __syncthreads();
  uint4* so4 = (uint4*)(sorted2 + s);
  const uint4* st4 = (const uint4*)stage;
  for (int j = threadIdx.x; j < cnt4; j += PBLK) so4[j] = st4[j];
  for (int j = cnt4 * 4 + threadIdx.x; j < cnt; j += PBLK) sorted2[s + j] = stage[j];
  // scale: s1b = bf16(hw * dis) for this bucket's nodes
#pragma unroll
  for (int g = 0; g < CB / PBLK; ++g) {
    int node = (b << CSH) + g * PBLK + (int)threadIdx.x;
    if (node < n) {
      float di = dis[node];
      uint4 a0 = hwb[(size_t)node * 2 + 0];
      uint4 a1 = hwb[(size_t)node * 2 + 1];
      unsigned w0 = f2bf(bflo(a0.x) * di) | (f2bf(bfhi(a0.x) * di) << 16);
      unsigned w1 = f2bf(bflo(a0.y) * di) | (f2bf(bfhi(a0.y) * di) << 16);
      unsigned w2 = f2bf(bflo(a0.z) * di) | (f2bf(bfhi(a0.z) * di) << 16);
      unsigned w3 = f2bf(bflo(a0.w) * di) | (f2bf(bfhi(a0.w) * di) << 16);
      unsigned w4 = f2bf(bflo(a1.x) * di) | (f2bf(bfhi(a1.x) * di) << 16);
      unsigned w5 = f2bf(bflo(a1.y) * di) | (f2bf(bfhi(a1.y) * di) << 16);
      unsigned w6 = f2bf(bflo(a1.z) * di) | (f2bf(bfhi(a1.z) * di) << 16);
      unsigned w7 = f2bf(bflo(a1.w) * di) | (f2bf(bfhi(a1.w) * di) << 16);
      s1b[(size_t)node * 2 + 0] = make_uint4(w0, w1, w2, w3);
      s1b[(size_t)node * 2 + 1] = make_uint4(w4, w5, w6, w7);
    }
  }
}

#define ACC8(V)                                         \
  acc[0] += bflo(V.x); acc[1] += bfhi(V.x);             \
  acc[2] += bflo(V.y); acc[3] += bfhi(V.y);             \
  acc[4] += bflo(V.z); acc[5] += bfhi(V.z);             \
  acc[6] += bflo(V.w); acc[7] += bfhi(V.w);

// ---------- layer 1: CSR run-walk, register accumulate, 2-deep prefetch + node2 ----------
__global__ __launch_bounds__(ABLK) void k_agg1(const unsigned* __restrict__ sorted2,
                                               const int2* __restrict__ noderng,
                                               const uint4* __restrict__ s1b,
                                               const float* __restrict__ dis,
                                               const float* __restrict__ b1,
                                               const float* __restrict__ W2,
                                               unsigned* __restrict__ s2b, int n) {
  const int q = threadIdx.x & 1;                       // 16B half of the 32B row
  const int node = blockIdx.x * (ABLK >> 1) + (threadIdx.x >> 1);
  if (node >= n) return;
  float di = dis[node];
  uint4 sv = s1b[(size_t)node * 2 + q];                // self term
  float acc[8] = {bflo(sv.x), bfhi(sv.x), bflo(sv.y), bfhi(sv.y),
                  bflo(sv.z), bfhi(sv.z), bflo(sv.w), bfhi(sv.w)};
  int2 rng = noderng[node];
  int i = rng.x;
  const int re = rng.y;
  const int len = re - i;
  if (len > 0) {
    uint4 v0 = s1b[(size_t)sorted2[i] * 2 + q];
    if (len > 1) {
      uint4 v1 = s1b[(size_t)sorted2[i + 1] * 2 + q];
      i += 2;
      while (i < re) {
        uint4 v2 = s1b[(size_t)sorted2[i] * 2 + q];    // 2-deep prefetch
        ACC8(v0);
        v0 = v1; v1 = v2;
        ++i;
      }
      ACC8(v0);
      v0 = v1;
    }
    ACC8(v0);
  }
  // node2 epilogue: lane owns feats f = q*8+k; h = relu(di*acc+b1); o = h@W2
  float p0 = 0.f, p1 = 0.f;
#pragma unroll
  for (int k = 0; k < 8; ++k) {
    int f = q * 8 + k;
    float h = fmaxf(fmaf(di, acc[k], b1[f]), 0.0f);
    p0 = fmaf(h, W2[f * 2 + 0], p0);
    p1 = fmaf(h, W2[f * 2 + 1], p1);
  }
  p0 += __shfl_xor(p0, 1);
  p1 += __shfl_xor(p1, 1);
  if (q == 0)
    s2b[node] = f2bf(p0 * di) | (f2bf(p1 * di) << 16);
}

// ---------- layer 2: CSR run-walk over bf16 s2 (L2-resident) + log_softmax ----------
__global__ __launch_bounds__(ABLK) void k_agg2(const unsigned* __restrict__ sorted2,
                                               const int2* __restrict__ noderng,
                                               const unsigned* __restrict__ s2b,
                                               const float* __restrict__ dis,
                                               const float* __restrict__ b2,
                                               float* __restrict__ out, int n) {
  const int node = blockIdx.x * ABLK + threadIdx.x;
  if (node >= n) return;
  float di = dis[node];
  unsigned sv = s2b[node];
  float a0 = bflo(sv), a1 = bfhi(sv);
  int2 rng = noderng[node];
  int i = rng.x;
  const int re = rng.y;
  const int len = re - i;
  if (len > 0) {
    unsigned v0 = s2b[sorted2[i]];
    if (len > 1) {
      unsigned v1 = s2b[sorted2[i + 1]];
      i += 2;
      while (i < re) {
        unsigned v2 = s2b[sorted2[i]];
        a0 += bflo(v0); a1 += bfhi(v0);
        v0 = v1; v1 = v2;
        ++i;
      }
      a0 += bflo(v0); a1 += bfhi(v0);
      v0 = v1;
    }
    a0 += bflo(v0); a1 += bfhi(v0);
  }
  float o0 = fmaf(di, a0, b2[0]);
  float o1 = fmaf(di, a1, b2[1]);
  float m = fmaxf(o0, o1);
  float lse = m + logf(expf(o0 - m) + expf(o1 - m));
  float2 r;
  r.x = o0 - lse;
  r.y = o1 - lse;
  ((float2*)out)[node] = r;
}

extern "C" void kernel_launch(void* const* d_in, const int* in_sizes, int n_in,
                              void* d_out, int out_size, void* d_ws, size_t ws_size,
                              hipStream_t stream) {
  const float* x  = (const float*)d_in[0];
  const float* W1 = (const float*)d_in[1];
  const float* b1 = (const float*)d_in[2];
  const float* W2 = (const float*)d_in[3];
  const float* b2 = (const float*)d_in[4];
  const int*   ei = (const int*)d_in[5];
  const int n = in_sizes[0] / F_INK;
  const int e = in_sizes[5] / 2;
  const int* rows = ei;      // edge_index[0] = source
  const int* cols = ei + e;  // edge_index[1] = target

  const int NC = (n + CB - 1) / CB;      // 489 coarse buckets
  const int nblk = (e + EPB - 1) / EPB;  // 245 partition blocks

  char* ws = (char*)d_ws;
  size_t off = 0;
  auto alloc = [&](size_t bytes) {
    void* p = ws + off;
    off = (off + bytes + 15) & ~(size_t)15;
    return p;
  };
  float* dis        = (float*)alloc((size_t)n * 4);
  uint4* hwb        = (uint4*)alloc((size_t)n * 32);          // bf16 hw (un-scaled)
  uint4* s1b        = (uint4*)alloc((size_t)n * 32);          // bf16 s1 = hw*dis
  unsigned* s2b     = (unsigned*)alloc((size_t)n * 4);        // bf16 s2, 4 B/node
  unsigned* epk     = (unsigned*)alloc((size_t)NC * CAPB * 4);    // padded, ~20 MB
  unsigned* sorted2 = (unsigned*)alloc((size_t)NC * CAPB * 4);    // padded, ~20 MB
  int2* noderng     = (int2*)alloc((size_t)n * 8);
  int* gcur         = (int*)alloc((size_t)NC * 4);
  float* outp = (float*)d_out;

  (void)hipMemsetAsync(gcur, 0, (size_t)NC * 4, stream);
  k_pre  <<<nblk + NC, PBLK, EPB * 4, stream>>>(rows, cols, gcur, epk, x, W1, hwb,
                                                e, n, NC, nblk);
  k_sortB<<<NC, PBLK, 0, stream>>>(epk, gcur, hwb, sorted2, noderng, dis, s1b, n);
  k_agg1 <<<(n + (ABLK / 2) - 1) / (ABLK / 2), ABLK, 0, stream>>>(sorted2, noderng, s1b,
                                                                  dis, b1, W2, s2b, n);
  k_agg2 <<<(n + ABLK - 1) / ABLK, ABLK, 0, stream>>>(sorted2, noderng, s2b, dis, b2,
                                                      outp, n);
}